// Round 10
// baseline (121.192 us; speedup 1.0000x reference)
//
#include <hip/hip_runtime.h>
#include <hip/hip_bf16.h>
#include <math.h>

typedef __attribute__((ext_vector_type(8))) short short8;
typedef __attribute__((ext_vector_type(4))) short short4v;
typedef __attribute__((ext_vector_type(4))) float float4v;

#define BB 4
#define TT 256
#define NDET 16
#define HH 256
#define NHEAD 8
#define DD 32
#define FFNDIM 1024
#define ROWS (BB*TT*NDET) /* 16384 */
#define EPS 1e-5f

// f32 -> bf16 round-to-nearest-even
__device__ __forceinline__ unsigned short f2bf(float f) {
  unsigned int u = __float_as_uint(f);
  u += 0x7fffu + ((u >> 16) & 1u);
  return (unsigned short)(u >> 16);
}
__device__ __forceinline__ float bf2f(unsigned short u) {
  return __uint_as_float((unsigned int)u << 16);
}
// v_exp_f32 computes 2^x natively
__device__ __forceinline__ float exp2v(float x) {
  float r; asm("v_exp_f32 %0, %1" : "=v"(r) : "v"(x)); return r;
}
// pack two f32 -> two bf16 in one reg (lo in low half)
__device__ __forceinline__ unsigned int cvtpk(float lo, float hi) {
  unsigned int r; asm("v_cvt_pk_bf16_f32 %0, %1, %2" : "=v"(r) : "v"(lo), "v"(hi)); return r;
}
// K=16 bf16 MFMA: A/B = 4 bf16 (2 VGPR), lane(lrow,g): A[m=lrow][k=g*4+e], B[k=g*4+e][n=lrow]
__device__ __forceinline__ float4v mfma16(short4v a, short4v b, float4v c) {
#if __has_builtin(__builtin_amdgcn_mfma_f32_16x16x16bf16_1k)
  return __builtin_amdgcn_mfma_f32_16x16x16bf16_1k(a, b, c, 0, 0, 0);
#elif __has_builtin(__builtin_amdgcn_mfma_f32_16x16x16_bf16)
  return __builtin_amdgcn_mfma_f32_16x16x16_bf16(a, b, c, 0, 0, 0);
#else
  float4v d;
  asm("v_mfma_f32_16x16x16_bf16 %0, %1, %2, %3"
      : "=v"(d) : "v"(a), "v"(b), "v"(c));
  return d;
#endif
}

// ---------------- prep: weight transposes + x cvt + kpm pack + bias concat ----------------
__device__ __forceinline__ void wt_tile(const float* __restrict__ W, unsigned short* __restrict__ WT,
                                        int K, int N, int k0, int n0,
                                        float (*tile)[33], int tid) {
  {
    int r = tid >> 3, c4 = (tid & 7) * 4;
    float4 in = *(const float4*)(W + (size_t)(k0 + r) * N + n0 + c4);
    tile[r][c4 + 0] = in.x; tile[r][c4 + 1] = in.y;
    tile[r][c4 + 2] = in.z; tile[r][c4 + 3] = in.w;
  }
  __syncthreads();
  {
    int n = tid >> 3, k4 = (tid & 7) * 4;
    ushort4 o;
    o.x = f2bf(tile[k4 + 0][n]); o.y = f2bf(tile[k4 + 1][n]);
    o.z = f2bf(tile[k4 + 2][n]); o.w = f2bf(tile[k4 + 3][n]);
    *(ushort4*)(WT + (size_t)(n0 + n) * K + k0 + k4) = o;
  }
}

__global__ void prep_kernel(const float* __restrict__ x, const unsigned char* __restrict__ kpm,
                            const float* __restrict__ Wq, const float* __restrict__ Wk,
                            const float* __restrict__ Wv, const float* __restrict__ W1,
                            const float* __restrict__ W2,
                            const float* __restrict__ bq, const float* __restrict__ bk,
                            const float* __restrict__ bv,
                            unsigned short* __restrict__ xb, unsigned short* __restrict__ WqkvT,
                            unsigned short* __restrict__ W1T, unsigned short* __restrict__ W2T,
                            unsigned short* __restrict__ kpm16, float* __restrict__ bqkv) {
  __shared__ float tile[32][33];
  int bid = blockIdx.x, tid = threadIdx.x;
  if (bid < 4096) {
    size_t i = (size_t)(bid * 256 + tid) * 4;
    float4 v = *(const float4*)(x + i);
    ushort4 o = { f2bf(v.x), f2bf(v.y), f2bf(v.z), f2bf(v.w) };
    *(ushort4*)(xb + i) = o;
  } else if (bid < 4288) {
    int t = bid - 4096;
    int wsel = t >> 6, tt = t & 63;
    const float* W = (wsel == 0) ? Wq : (wsel == 1) ? Wk : Wv;
    wt_tile(W, WqkvT + wsel * 65536, 256, 256, (tt >> 3) * 32, (tt & 7) * 32, tile, tid);
  } else if (bid < 4544) {
    int tt = bid - 4288; // W1 [256][1024]
    wt_tile(W1, W1T, 256, 1024, (tt >> 5) * 32, (tt & 31) * 32, tile, tid);
  } else if (bid < 4800) {
    int tt = bid - 4544; // W2 [1024][256]
    wt_tile(W2, W2T, 1024, 256, (tt >> 3) * 32, (tt & 7) * 32, tile, tid);
  } else if (bid < 4804) {
    int w = (bid - 4800) * 256 + tid;
    uint4 u = *(const uint4*)(kpm + (size_t)w * 16);
    unsigned int a[4] = {u.x, u.y, u.z, u.w};
    unsigned int bits = 0;
#pragma unroll
    for (int m = 0; m < 16; ++m)
      if ((a[m >> 2] >> ((m & 3) * 8)) & 0xffu) bits |= (1u << m);
    kpm16[w] = (unsigned short)bits;
  } else {
    bqkv[tid] = bq[tid];
    bqkv[256 + tid] = bk[tid];
    bqkv[512 + tid] = bv[tid];
  }
}

// -------- stage NROWS x 64 bf16 cols from row-major src (stride K) into LDS --------
// LDS linear [r][128B]; source pre-swizzled so swizzled ds_read works (rule #21).
template<int NROWS, int K, int NT>
__device__ __forceinline__ void stage_rows(const unsigned short* __restrict__ src, int kcol0,
                                           char* ldsbase, int tid) {
  constexpr int ISS = NROWS * 8 / NT;
  int wave = tid >> 6;
#pragma unroll
  for (int i = 0; i < ISS; ++i) {
    int flat = i * (NT * 16) + tid * 16;
    int r = flat >> 7;
    int cb = flat & 127;
    int scb = cb ^ ((r & 7) << 4);
    const unsigned short* g = src + (size_t)r * K + kcol0 + (scb >> 1);
    char* l = ldsbase + i * (NT * 16) + wave * 1024; // wave-uniform; HW adds lane*16
    __builtin_amdgcn_global_load_lds((const __attribute__((address_space(1))) void*)g,
                                     (__attribute__((address_space(3))) void*)l, 16, 0, 0);
  }
}

// ---------------- MFMA GEMM (m97 structure), 256 thr, tile 128x128 ----------------
// EPI 0: QKV fused (N=768): (acc+bias)*scale -> q/k head-major bf16, V written pre-transposed vT
// EPI 1: relu(acc+bias) -> bf16 hid [M][1024]
template<int EPI>
__launch_bounds__(256, 2)
__global__ void gemm_kernel(const unsigned short* __restrict__ A,
                            const unsigned short* __restrict__ Bt,
                            const float* __restrict__ bias,
                            unsigned short* __restrict__ q_o, unsigned short* __restrict__ k_o,
                            unsigned short* __restrict__ vT_o,
                            unsigned short* __restrict__ outb) {
  constexpr int BM = 128, BN = 128, K = 256, KP = K / 64;
  __shared__ char smem[(BM + BN) * 128];
  const int tid = threadIdx.x;
  const int wave = tid >> 6, lane = tid & 63;
  const int lrow = lane & 15, g = lane >> 4;
  const int m0 = blockIdx.x * BM;
  const int n0 = blockIdx.y * BN;
  const int wr = wave >> 1, wc = wave & 1;
  char* As = smem;
  char* Bs = smem + BM * 128;
  float4v acc[4][4];
#pragma unroll
  for (int i = 0; i < 4; ++i)
#pragma unroll
    for (int j = 0; j < 4; ++j) acc[i][j] = (float4v){0.f, 0.f, 0.f, 0.f};

  const unsigned short* Abase = A + (size_t)m0 * K;
  const unsigned short* Bbase = Bt + (size_t)n0 * K;
  for (int ph = 0; ph < KP; ++ph) {
    if (ph) __syncthreads();
    stage_rows<BM, K, 256>(Abase, ph * 64, As, tid);
    stage_rows<BN, K, 256>(Bbase, ph * 64, Bs, tid);
    __syncthreads();
#pragma unroll
    for (int ks = 0; ks < 2; ++ks) {
      short8 af[4], bf[4];
#pragma unroll
      for (int i = 0; i < 4; ++i) {
        int ar = wr * 64 + i * 16 + lrow;
        af[i] = *(const short8*)(As + ar * 128 + ((ks * 64 + g * 16) ^ ((ar & 7) << 4)));
      }
#pragma unroll
      for (int j = 0; j < 4; ++j) {
        int br = wc * 64 + j * 16 + lrow;
        bf[j] = *(const short8*)(Bs + br * 128 + ((ks * 64 + g * 16) ^ ((br & 7) << 4)));
      }
#pragma unroll
      for (int i = 0; i < 4; ++i)
#pragma unroll
        for (int j = 0; j < 4; ++j)
          acc[i][j] = __builtin_amdgcn_mfma_f32_16x16x32_bf16(af[i], bf[j], acc[i][j], 0, 0, 0);
    }
  }

  if (EPI == 0) {
    const float QS = 0.17677669529663687f * 1.4426950408889634f; // (1/sqrt(32))*log2(e)
#pragma unroll
    for (int i = 0; i < 4; ++i)
#pragma unroll
      for (int j = 0; j < 4; ++j) {
        int C = n0 + wc * 64 + j * 16 + lrow;
        float bv = bias[C];
        int proj = C >> 8, cc = C & 255;  // wave-uniform proj
        int h = cc >> 5, d = cc & 31;
        if (proj == 2) { // V: write pre-transposed vT[bh][d][tn], 4 consecutive tn packed
          int grow0 = m0 + wr * 64 + i * 16 + g * 4;
          int b = grow0 >> 12, tn0 = grow0 & 4095;
          ushort4 o;
          o.x = f2bf(acc[i][j][0] + bv);
          o.y = f2bf(acc[i][j][1] + bv);
          o.z = f2bf(acc[i][j][2] + bv);
          o.w = f2bf(acc[i][j][3] + bv);
          *(ushort4*)(vT_o + ((size_t)(b * 8 + h) * 32 + d) * 4096 + tn0) = o;
        } else {
          unsigned short* om = (proj == 0) ? q_o : k_o;
          float sc = (proj == 0) ? QS : 1.f;
#pragma unroll
          for (int r = 0; r < 4; ++r) {
            int grow = m0 + wr * 64 + i * 16 + g * 4 + r;
            int b = grow >> 12, tn = grow & 4095;
            om[(size_t)((b * 8 + h) * 4096 + tn) * 32 + d] = f2bf((acc[i][j][r] + bv) * sc);
          }
        }
      }
  } else {
#pragma unroll
    for (int i = 0; i < 4; ++i)
#pragma unroll
      for (int j = 0; j < 4; ++j) {
        int C = n0 + wc * 64 + j * 16 + lrow;
        float bv = bias[C];
#pragma unroll
        for (int r = 0; r < 4; ++r) {
          int grow = m0 + wr * 64 + i * 16 + g * 4 + r;
          outb[(size_t)grow * FFNDIM + C] = f2bf(fmaxf(acc[i][j][r] + bv, 0.f));
        }
      }
  }
}

// ---------------- windowed attention + residual + LN1 fused, register-resident P ----------------
// One 512-thread block per (b,t): 8 waves = 8 heads. Deep explicit MLP: K batch -> QK^T;
// V+residual batch issued, then sched_barrier(0) pins them ABOVE the softmax (the compiler
// sank these loads into the PV loop in R9 -> re-serialized latency; the barrier forbids that).
__launch_bounds__(512, 2)
__global__ void attn_ln_kernel(const unsigned short* __restrict__ qb,
                               const unsigned short* __restrict__ kb,
                               const unsigned short* __restrict__ vT,
                               const unsigned short* __restrict__ kpm16,
                               const unsigned short* __restrict__ xb,
                               const float* __restrict__ gw, const float* __restrict__ bw,
                               unsigned short* __restrict__ yb) {
  __shared__ float stats[8][16][2];
  __shared__ float mst[16], rst[16];
  int tid = threadIdx.x;
  int wave = tid >> 6, l = tid & 63;
  // XCD-bijective swizzle: each XCD gets 128 consecutive (b,t) blocks -> K/V window reuse in-L2
  int lid = (blockIdx.x & 7) * 128 + (blockIdx.x >> 3);
  int t = lid & 255, b = lid >> 8;
  int lrow = l & 15, g = l >> 4;
  size_t base = (size_t)(b * 8 + wave) * 4096;
  const float4v z4 = {0.f, 0.f, 0.f, 0.f};

  // ---- prefetch Q + mask words ----
  short8 qf = *(const short8*)(qb + (base + t * 16 + lrow) * 32 + g * 8);
  unsigned int mw[17];
#pragma unroll
  for (int w = 0; w < 17; ++w) {
    int j = t + w - 8;
    mw[w] = (j >= 0 && j < 256) ? (unsigned int)kpm16[b * 256 + j] : 0xffffu;
  }

  // ---- K prefetch: all 17 frags in flight (clamped addr; OOB rows masked) ----
  short8 kfA[9], kfB[8];
#pragma unroll
  for (int w = 0; w < 9; ++w) {
    int j = min(max(t + w - 8, 0), 255);
    kfA[w] = *(const short8*)(kb + (base + j * 16 + lrow) * 32 + g * 8);
  }
#pragma unroll
  for (int w = 0; w < 8; ++w) {
    int j = min(max(t + w + 1, 0), 255);
    kfB[w] = *(const short8*)(kb + (base + j * 16 + lrow) * 32 + g * 8);
  }

  // ---- QK^T: 17 back-to-back MFMAs ----
  float4v s[17];
  __builtin_amdgcn_s_setprio(1);
#pragma unroll
  for (int w = 0; w < 9; ++w)
    s[w] = __builtin_amdgcn_mfma_f32_16x16x32_bf16(kfA[w], qf, z4, 0, 0, 0);
#pragma unroll
  for (int w = 0; w < 8; ++w)
    s[9 + w] = __builtin_amdgcn_mfma_f32_16x16x32_bf16(kfB[w], qf, z4, 0, 0, 0);
  __builtin_amdgcn_s_setprio(0);

  // ---- V prefetch: all 34 8B loads issued NOW; latency hides under softmax VALU ----
  int tn0 = (t - 8) * 16;
  const unsigned short* vb0 = vT + ((size_t)(b * 8 + wave) * 32 + lrow) * 4096 + tn0 + g * 4;
  uint2 v0[17], v1[17];
#pragma unroll
  for (int w = 0; w < 17; ++w) {
    v0[w] = *(const uint2*)(vb0 + w * 16);
    v1[w] = *(const uint2*)(vb0 + (size_t)16 * 4096 + w * 16);
  }
  // residual preload (consumed at the very end)
  size_t rowbase = (size_t)(b * 256 + t) * 16 * 256;
  int col = wave * 32 + lrow;
  float xv0[4], xv1[4];
#pragma unroll
  for (int r = 0; r < 4; ++r) {
    xv0[r] = bf2f(xb[rowbase + (g * 4 + r) * 256 + col]);
    xv1[r] = bf2f(xb[rowbase + (g * 4 + r) * 256 + col + 16]);
  }
  // Pin: the loads above must ISSUE here; softmax below must not move above.
  __builtin_amdgcn_sched_barrier(0);

  // ---- mask + softmax (logits pre-scaled by log2 e) ----
  float mx = -INFINITY;
#pragma unroll
  for (int w = 0; w < 17; ++w) {
    unsigned int mwn = mw[w] >> (g * 4);
#pragma unroll
    for (int r = 0; r < 4; ++r) {
      if ((mwn >> r) & 1u) s[w][r] = -3.0e38f;
      mx = fmaxf(mx, s[w][r]);
    }
  }
  mx = fmaxf(mx, __shfl_xor(mx, 16));
  mx = fmaxf(mx, __shfl_xor(mx, 32));
  float sum = 0.f;
#pragma unroll
  for (int w = 0; w < 17; ++w)
#pragma unroll
    for (int r = 0; r < 4; ++r) {
      float e = exp2v(s[w][r] - mx);
      s[w][r] = e; sum += e;
    }
  sum += __shfl_xor(sum, 16);
  sum += __shfl_xor(sum, 32);
  float inv = 1.f / sum;

  // ---- pre-pack P to bf16 (frees s before PV; PV = pure register MFMAs) ----
  uint2 pw[17];
#pragma unroll
  for (int w = 0; w < 17; ++w) {
    pw[w].x = cvtpk(s[w][0], s[w][1]);
    pw[w].y = cvtpk(s[w][2], s[w][3]);
  }

  // ---- PV: 34 back-to-back K=16 MFMAs ----
  float4v o0 = z4, o1 = z4;
  __builtin_amdgcn_s_setprio(1);
#pragma unroll
  for (int w = 0; w < 17; ++w) {
    short4v pwv = *(short4v*)&pw[w];
    o0 = mfma16(pwv, *(short4v*)&v0[w], o0);
    o1 = mfma16(pwv, *(short4v*)&v1[w], o1);
  }
  __builtin_amdgcn_s_setprio(0);

  // ---- residual + cross-wave LN over 256 cols ----
  float va0[4], va1[4];
#pragma unroll
  for (int r = 0; r < 4; ++r) {
    float invn = __shfl(inv, g * 4 + r);
    va0[r] = o0[r] * invn + xv0[r];
    va1[r] = o1[r] * invn + xv1[r];
  }
#pragma unroll
  for (int r = 0; r < 4; ++r) {
    float sm = va0[r] + va1[r];
    float sq = va0[r] * va0[r] + va1[r] * va1[r];
#pragma unroll
    for (int off = 1; off < 16; off <<= 1) {
      sm += __shfl_xor(sm, off);
      sq += __shfl_xor(sq, off);
    }
    if (lrow == 0) {
      stats[wave][g * 4 + r][0] = sm;
      stats[wave][g * 4 + r][1] = sq;
    }
  }
  __syncthreads();
  if (tid < 16) {
    float S = 0.f, Q = 0.f;
#pragma unroll
    for (int w2 = 0; w2 < 8; ++w2) { S += stats[w2][tid][0]; Q += stats[w2][tid][1]; }
    float mean = S * (1.f / 256.f);
    float var = Q * (1.f / 256.f) - mean * mean;
    mst[tid] = mean;
    rst[tid] = rsqrtf(var + EPS);
  }
  __syncthreads();
  float gv0 = gw[col], gv1 = gw[col + 16];
  float bv0 = bw[col], bv1 = bw[col + 16];
#pragma unroll
  for (int r = 0; r < 4; ++r) {
    int row = g * 4 + r;
    float mean = mst[row], rs = rst[row];
    yb[rowbase + row * 256 + col]      = f2bf((va0[r] - mean) * rs * gv0 + bv0);
    yb[rowbase + row * 256 + col + 16] = f2bf((va1[r] - mean) * rs * gv1 + bv1);
  }
}

// ---------------- FFN2 + residual + LN2, 512 thr, register-LN stats ----------------
__launch_bounds__(512, 2)
__global__ void ffn2_kernel(const unsigned short* __restrict__ hid,
                            const unsigned short* __restrict__ W2T,
                            const float* __restrict__ b2,
                            const unsigned short* __restrict__ yb,
                            const float* __restrict__ gw, const float* __restrict__ bw,
                            float* __restrict__ out) {
  constexpr int BM = 64, BN = 256, K = 1024, KP = K / 64;
  __shared__ char smem[(BM + BN) * 128]; // 40KB
  __shared__ float stats[8][32][2];
  __shared__ float mst[64], rst[64];
  const int tid = threadIdx.x;
  const int wave = tid >> 6, lane = tid & 63;
  const int lrow = lane & 15, g = lane >> 4;
  const int m0 = blockIdx.x * BM;
  const int wr = wave >> 2, wc = wave & 3; // 2M x 4N waves, wave tile 32x64
  char* As = smem;
  char* Bs = smem + BM * 128;
  float4v acc[2][4];
#pragma unroll
  for (int i = 0; i < 2; ++i)
#pragma unroll
    for (int j = 0; j < 4; ++j) acc[i][j] = (float4v){0.f, 0.f, 0.f, 0.f};

  const unsigned short* Abase = hid + (size_t)m0 * K;
  for (int ph = 0; ph < KP; ++ph) {
    if (ph) __syncthreads();
    stage_rows<BM, K, 512>(Abase, ph * 64, As, tid);
    stage_rows<BN, K, 512>(W2T, ph * 64, Bs, tid);
    __syncthreads();
#pragma unroll
    for (int ks = 0; ks < 2; ++ks) {
      short8 af[2], bf[4];
#pragma unroll
      for (int i = 0; i < 2; ++i) {
        int ar = wr * 32 + i * 16 + lrow;
        af[i] = *(const short8*)(As + ar * 128 + ((ks * 64 + g * 16) ^ ((ar & 7) << 4)));
      }
#pragma unroll
      for (int j = 0; j < 4; ++j) {
        int br = wc * 64 + j * 16 + lrow;
        bf[j] = *(const short8*)(Bs + br * 128 + ((ks * 64 + g * 16) ^ ((br & 7) << 4)));
      }
#pragma unroll
      for (int i = 0; i < 2; ++i)
#pragma unroll
        for (int j = 0; j < 4; ++j)
          acc[i][j] = __builtin_amdgcn_mfma_f32_16x16x32_bf16(af[i], bf[j], acc[i][j], 0, 0, 0);
    }
  }
  __syncthreads(); // staging LDS dead; safe to use stats

#pragma unroll
  for (int i = 0; i < 2; ++i)
#pragma unroll
    for (int j = 0; j < 4; ++j) {
      int col = wc * 64 + j * 16 + lrow;
      float bv = b2[col];
#pragma unroll
      for (int r = 0; r < 4; ++r) {
        int row = wr * 32 + i * 16 + g * 4 + r;
        acc[i][j][r] += bv + bf2f(yb[(size_t)(m0 + row) * 256 + col]);
      }
    }
#pragma unroll
  for (int i = 0; i < 2; ++i)
#pragma unroll
    for (int r = 0; r < 4; ++r) {
      float sm = acc[i][0][r] + acc[i][1][r] + acc[i][2][r] + acc[i][3][r];
      float sq = acc[i][0][r] * acc[i][0][r] + acc[i][1][r] * acc[i][1][r]
               + acc[i][2][r] * acc[i][2][r] + acc[i][3][r] * acc[i][3][r];
#pragma unroll
      for (int off = 1; off < 16; off <<= 1) {
        sm += __shfl_xor(sm, off);
        sq += __shfl_xor(sq, off);
      }
      if (lrow == 0) {
        stats[wave][i * 16 + g * 4 + r][0] = sm;
        stats[wave][i * 16 + g * 4 + r][1] = sq;
      }
    }
  __syncthreads();
  if (tid < 64) {
    int wrr = tid >> 5, rl = tid & 31;
    float S = 0.f, Q = 0.f;
#pragma unroll
    for (int w2 = 0; w2 < 4; ++w2) {
      S += stats[wrr * 4 + w2][rl][0];
      Q += stats[wrr * 4 + w2][rl][1];
    }
    float mean = S * (1.f / 256.f);
    float var = Q * (1.f / 256.f) - mean * mean;
    mst[tid] = mean;
    rst[tid] = rsqrtf(var + EPS);
  }
  __syncthreads();
  float gv[4], bev[4];
#pragma unroll
  for (int j = 0; j < 4; ++j) {
    int col = wc * 64 + j * 16 + lrow;
    gv[j] = gw[col]; bev[j] = bw[col];
  }
#pragma unroll
  for (int i = 0; i < 2; ++i)
#pragma unroll
    for (int r = 0; r < 4; ++r) {
      int rl = wr * 32 + i * 16 + g * 4 + r;
      float mean = mst[rl], rs = rst[rl];
#pragma unroll
      for (int j = 0; j < 4; ++j) {
        int col = wc * 64 + j * 16 + lrow;
        out[(size_t)(m0 + rl) * 256 + col] = (acc[i][j][r] - mean) * rs * gv[j] + bev[j];
      }
    }
}

extern "C" void kernel_launch(void* const* d_in, const int* in_sizes, int n_in,
                              void* d_out, int out_size, void* d_ws, size_t ws_size,
                              hipStream_t stream) {
  const float* x  = (const float*)d_in[0];
  const unsigned char* kpm = (const unsigned char*)d_in[1];
  const float* Wq = (const float*)d_in[2];
  const float* bq = (const float*)d_in[3];
  const float* Wk = (const float*)d_in[4];
  const float* bk = (const float*)d_in[5];
  const float* Wv = (const float*)d_in[6];
  const float* bv = (const float*)d_in[7];
  const float* W1 = (const float*)d_in[8];
  const float* b1 = (const float*)d_in[9];
  const float* W2 = (const float*)d_in[10];
  const float* b2 = (const float*)d_in[11];
  const float* g1 = (const float*)d_in[12];
  const float* be1= (const float*)d_in[13];
  const float* g2 = (const float*)d_in[14];
  const float* be2= (const float*)d_in[15];
  float* out = (float*)d_out;

  char* w = (char*)d_ws;
  const size_t MB = 1u << 20;
  unsigned short* xb   = (unsigned short*)(w);            // 8MB
  unsigned short* qhm  = (unsigned short*)(w + 8 * MB);   // 8MB
  unsigned short* khm  = (unsigned short*)(w + 16 * MB);  // 8MB
  unsigned short* vTb  = (unsigned short*)(w + 24 * MB);  // 8MB
  unsigned short* yb   = (unsigned short*)(w + 48 * MB);  // 8MB
  unsigned short* WqkvT = (unsigned short*)(w + 72 * MB); // 384KB [768][256]
  unsigned short* W1T = WqkvT + 196608;                   // 512KB [1024][256]
  unsigned short* W2T = W1T + 262144;                     // 512KB [256][1024]
  unsigned short* kpm16 = W2T + 262144;                   // 2KB
  float* bqkv = (float*)(kpm16 + 1024);                   // 3KB
  unsigned short* hid = qhm;                              // 32MB overlay 8..40MB (q/k/vT dead after attn)

  prep_kernel<<<4805, 256, 0, stream>>>(x, kpm, Wq, Wk, Wv, W1, W2, bq, bk, bv,
                                        xb, WqkvT, W1T, W2T, kpm16, bqkv);
  gemm_kernel<0><<<dim3(128, 6), 256, 0, stream>>>(xb, WqkvT, bqkv, qhm, khm, vTb, nullptr);
  attn_ln_kernel<<<1024, 512, 0, stream>>>(qhm, khm, vTb, kpm16, xb, g1, be1, yb);
  gemm_kernel<1><<<dim3(128, 8), 256, 0, stream>>>(yb, W1T, b1, nullptr, nullptr, nullptr, hid);
  ffn2_kernel<<<256, 512, 0, stream>>>(hid, W2T, b2, yb, g2, be2, out);
}

// Round 11
// 102.221 us; speedup vs baseline: 1.1856x; 1.1856x over previous
//
#include <hip/hip_runtime.h>
#include <hip/hip_bf16.h>
#include <math.h>

typedef __attribute__((ext_vector_type(8))) short short8;
typedef __attribute__((ext_vector_type(4))) float float4v;

#define BB 4
#define TT 256
#define NDET 16
#define HH 256
#define NHEAD 8
#define DD 32
#define FFNDIM 1024
#define ROWS (BB*TT*NDET) /* 16384 */
#define EPS 1e-5f

// f32 -> bf16 round-to-nearest-even
__device__ __forceinline__ unsigned short f2bf(float f) {
  unsigned int u = __float_as_uint(f);
  u += 0x7fffu + ((u >> 16) & 1u);
  return (unsigned short)(u >> 16);
}
__device__ __forceinline__ float bf2f(unsigned short u) {
  return __uint_as_float((unsigned int)u << 16);
}
// v_exp_f32 computes 2^x natively
__device__ __forceinline__ float exp2v(float x) {
  float r; asm("v_exp_f32 %0, %1" : "=v"(r) : "v"(x)); return r;
}
// pack two f32 -> two bf16 in one reg (lo in low half)
__device__ __forceinline__ unsigned int cvtpk(float lo, float hi) {
  unsigned int r; asm("v_cvt_pk_bf16_f32 %0, %1, %2" : "=v"(r) : "v"(lo), "v"(hi)); return r;
}

// ---------------- prep: weight transposes + x cvt + kpm pack + bias concat ----------------
__device__ __forceinline__ void wt_tile(const float* __restrict__ W, unsigned short* __restrict__ WT,
                                        int K, int N, int k0, int n0,
                                        float (*tile)[33], int tid) {
  {
    int r = tid >> 3, c4 = (tid & 7) * 4;
    float4 in = *(const float4*)(W + (size_t)(k0 + r) * N + n0 + c4);
    tile[r][c4 + 0] = in.x; tile[r][c4 + 1] = in.y;
    tile[r][c4 + 2] = in.z; tile[r][c4 + 3] = in.w;
  }
  __syncthreads();
  {
    int n = tid >> 3, k4 = (tid & 7) * 4;
    ushort4 o;
    o.x = f2bf(tile[k4 + 0][n]); o.y = f2bf(tile[k4 + 1][n]);
    o.z = f2bf(tile[k4 + 2][n]); o.w = f2bf(tile[k4 + 3][n]);
    *(ushort4*)(WT + (size_t)(n0 + n) * K + k0 + k4) = o;
  }
}

__global__ void prep_kernel(const float* __restrict__ x, const unsigned char* __restrict__ kpm,
                            const float* __restrict__ Wq, const float* __restrict__ Wk,
                            const float* __restrict__ Wv, const float* __restrict__ W1,
                            const float* __restrict__ W2,
                            const float* __restrict__ bq, const float* __restrict__ bk,
                            const float* __restrict__ bv,
                            unsigned short* __restrict__ xb, unsigned short* __restrict__ WqkvT,
                            unsigned short* __restrict__ W1T, unsigned short* __restrict__ W2T,
                            unsigned short* __restrict__ kpm16, float* __restrict__ bqkv) {
  __shared__ float tile[32][33];
  int bid = blockIdx.x, tid = threadIdx.x;
  if (bid < 4096) {
    size_t i = (size_t)(bid * 256 + tid) * 4;
    float4 v = *(const float4*)(x + i);
    ushort4 o = { f2bf(v.x), f2bf(v.y), f2bf(v.z), f2bf(v.w) };
    *(ushort4*)(xb + i) = o;
  } else if (bid < 4288) {
    int t = bid - 4096;
    int wsel = t >> 6, tt = t & 63;
    const float* W = (wsel == 0) ? Wq : (wsel == 1) ? Wk : Wv;
    wt_tile(W, WqkvT + wsel * 65536, 256, 256, (tt >> 3) * 32, (tt & 7) * 32, tile, tid);
  } else if (bid < 4544) {
    int tt = bid - 4288; // W1 [256][1024]
    wt_tile(W1, W1T, 256, 1024, (tt >> 5) * 32, (tt & 31) * 32, tile, tid);
  } else if (bid < 4800) {
    int tt = bid - 4544; // W2 [1024][256]
    wt_tile(W2, W2T, 1024, 256, (tt >> 3) * 32, (tt & 7) * 32, tile, tid);
  } else if (bid < 4804) {
    int w = (bid - 4800) * 256 + tid;
    uint4 u = *(const uint4*)(kpm + (size_t)w * 16);
    unsigned int a[4] = {u.x, u.y, u.z, u.w};
    unsigned int bits = 0;
#pragma unroll
    for (int m = 0; m < 16; ++m)
      if ((a[m >> 2] >> ((m & 3) * 8)) & 0xffu) bits |= (1u << m);
    kpm16[w] = (unsigned short)bits;
  } else {
    bqkv[tid] = bq[tid];
    bqkv[256 + tid] = bk[tid];
    bqkv[512 + tid] = bv[tid];
  }
}

// -------- stage NROWS x 64 bf16 cols from row-major src (stride K) into LDS --------
// LDS linear [r][128B]; source pre-swizzled so swizzled ds_read works (rule #21).
template<int NROWS, int K, int NT>
__device__ __forceinline__ void stage_rows(const unsigned short* __restrict__ src, int kcol0,
                                           char* ldsbase, int tid) {
  constexpr int ISS = NROWS * 8 / NT;
  int wave = tid >> 6;
#pragma unroll
  for (int i = 0; i < ISS; ++i) {
    int flat = i * (NT * 16) + tid * 16;
    int r = flat >> 7;
    int cb = flat & 127;
    int scb = cb ^ ((r & 7) << 4);
    const unsigned short* g = src + (size_t)r * K + kcol0 + (scb >> 1);
    char* l = ldsbase + i * (NT * 16) + wave * 1024; // wave-uniform; HW adds lane*16
    __builtin_amdgcn_global_load_lds((const __attribute__((address_space(1))) void*)g,
                                     (__attribute__((address_space(3))) void*)l, 16, 0, 0);
  }
}

// ---------------- MFMA GEMM (m97 structure), 256 thr, tile 128x128 ----------------
// EPI 0: QKV fused (N=768): (acc+bias)*scale -> q/k head-major bf16, V written pre-transposed vT
// EPI 1: relu(acc+bias) -> bf16 hid [M][1024]
template<int EPI>
__launch_bounds__(256, 2)
__global__ void gemm_kernel(const unsigned short* __restrict__ A,
                            const unsigned short* __restrict__ Bt,
                            const float* __restrict__ bias,
                            unsigned short* __restrict__ q_o, unsigned short* __restrict__ k_o,
                            unsigned short* __restrict__ vT_o,
                            unsigned short* __restrict__ outb) {
  constexpr int BM = 128, BN = 128, K = 256, KP = K / 64;
  __shared__ char smem[(BM + BN) * 128];
  const int tid = threadIdx.x;
  const int wave = tid >> 6, lane = tid & 63;
  const int lrow = lane & 15, g = lane >> 4;
  const int m0 = blockIdx.x * BM;
  const int n0 = blockIdx.y * BN;
  const int wr = wave >> 1, wc = wave & 1;
  char* As = smem;
  char* Bs = smem + BM * 128;
  float4v acc[4][4];
#pragma unroll
  for (int i = 0; i < 4; ++i)
#pragma unroll
    for (int j = 0; j < 4; ++j) acc[i][j] = (float4v){0.f, 0.f, 0.f, 0.f};

  const unsigned short* Abase = A + (size_t)m0 * K;
  const unsigned short* Bbase = Bt + (size_t)n0 * K;
  for (int ph = 0; ph < KP; ++ph) {
    if (ph) __syncthreads();
    stage_rows<BM, K, 256>(Abase, ph * 64, As, tid);
    stage_rows<BN, K, 256>(Bbase, ph * 64, Bs, tid);
    __syncthreads();
#pragma unroll
    for (int ks = 0; ks < 2; ++ks) {
      short8 af[4], bf[4];
#pragma unroll
      for (int i = 0; i < 4; ++i) {
        int ar = wr * 64 + i * 16 + lrow;
        af[i] = *(const short8*)(As + ar * 128 + ((ks * 64 + g * 16) ^ ((ar & 7) << 4)));
      }
#pragma unroll
      for (int j = 0; j < 4; ++j) {
        int br = wc * 64 + j * 16 + lrow;
        bf[j] = *(const short8*)(Bs + br * 128 + ((ks * 64 + g * 16) ^ ((br & 7) << 4)));
      }
#pragma unroll
      for (int i = 0; i < 4; ++i)
#pragma unroll
        for (int j = 0; j < 4; ++j)
          acc[i][j] = __builtin_amdgcn_mfma_f32_16x16x32_bf16(af[i], bf[j], acc[i][j], 0, 0, 0);
    }
  }

  if (EPI == 0) {
    const float QS = 0.17677669529663687f * 1.4426950408889634f; // (1/sqrt(32))*log2(e)
#pragma unroll
    for (int i = 0; i < 4; ++i)
#pragma unroll
      for (int j = 0; j < 4; ++j) {
        int C = n0 + wc * 64 + j * 16 + lrow;
        float bv = bias[C];
        int proj = C >> 8, cc = C & 255;  // wave-uniform proj
        int h = cc >> 5, d = cc & 31;
        if (proj == 2) { // V: write pre-transposed vT[bh][d][tn], 4 consecutive tn packed
          int grow0 = m0 + wr * 64 + i * 16 + g * 4;
          int b = grow0 >> 12, tn0 = grow0 & 4095;
          ushort4 o;
          o.x = f2bf(acc[i][j][0] + bv);
          o.y = f2bf(acc[i][j][1] + bv);
          o.z = f2bf(acc[i][j][2] + bv);
          o.w = f2bf(acc[i][j][3] + bv);
          *(ushort4*)(vT_o + ((size_t)(b * 8 + h) * 32 + d) * 4096 + tn0) = o;
        } else {
          unsigned short* om = (proj == 0) ? q_o : k_o;
          float sc = (proj == 0) ? QS : 1.f;
#pragma unroll
          for (int r = 0; r < 4; ++r) {
            int grow = m0 + wr * 64 + i * 16 + g * 4 + r;
            int b = grow >> 12, tn = grow & 4095;
            om[(size_t)((b * 8 + h) * 4096 + tn) * 32 + d] = f2bf((acc[i][j][r] + bv) * sc);
          }
        }
      }
  } else {
#pragma unroll
    for (int i = 0; i < 4; ++i)
#pragma unroll
      for (int j = 0; j < 4; ++j) {
        int C = n0 + wc * 64 + j * 16 + lrow;
        float bv = bias[C];
#pragma unroll
        for (int r = 0; r < 4; ++r) {
          int grow = m0 + wr * 64 + i * 16 + g * 4 + r;
          outb[(size_t)grow * FFNDIM + C] = f2bf(fmaxf(acc[i][j][r] + bv, 0.f));
        }
      }
  }
}

// ---------------- windowed attention + residual + LN1 fused (R5 base + XCD swizzle) ----------------
// One 512-thread block per (b,t): 8 waves = 8 heads; block owns full 256-col rows
// for its 16 detections -> ctx never touches HBM; LN1 via cross-wave stats LDS.
__launch_bounds__(512, 4)
__global__ void attn_ln_kernel(const unsigned short* __restrict__ qb,
                               const unsigned short* __restrict__ kb,
                               const unsigned short* __restrict__ vT,
                               const unsigned short* __restrict__ kpm16,
                               const unsigned short* __restrict__ xb,
                               const float* __restrict__ gw, const float* __restrict__ bw,
                               unsigned short* __restrict__ yb) {
  __shared__ char Pall[8][9216]; // per-wave [16 n][288 key] bf16, 576B rows, 64B-closed swizzle
  __shared__ float stats[8][16][2];
  __shared__ float mst[16], rst[16];
  int tid = threadIdx.x;
  int wave = tid >> 6, l = tid & 63;
  // XCD-bijective swizzle (proven in R6: FETCH 78->17MB): each XCD gets 128 consecutive
  // (b,t) blocks so the 17-frame K/V windows of neighboring t stay in one XCD's L2.
  int lid = (blockIdx.x & 7) * 128 + (blockIdx.x >> 3);
  int t = lid & 255, b = lid >> 8;
  char* P = Pall[wave];
  int lrow = l & 15, g = l >> 4;
  int swz = (lrow & 3) << 4; // closed within 64B blocks (~4-way conflicts, buys occupancy)
  size_t base = (size_t)(b * 8 + wave) * 4096;
  short8 qf = *(const short8*)(qb + (base + t * 16 + lrow) * 32 + g * 8);
  const float4v z4 = {0.f, 0.f, 0.f, 0.f};
  float4v s[17];
  float mx = -INFINITY;
#pragma unroll
  for (int w = 0; w < 17; ++w) {
    int j = t + w - 8;
    if (j >= 0 && j < 256) {
      short8 kf = *(const short8*)(kb + (base + j * 16 + lrow) * 32 + g * 8);
      float4v sv = __builtin_amdgcn_mfma_f32_16x16x32_bf16(kf, qf, z4, 0, 0, 0);
      unsigned int mw = kpm16[b * 256 + j];
#pragma unroll
      for (int r = 0; r < 4; ++r)
        if ((mw >> (g * 4 + r)) & 1u) sv[r] = -INFINITY;
      s[w] = sv;
#pragma unroll
      for (int r = 0; r < 4; ++r) mx = fmaxf(mx, sv[r]);
    } else {
      s[w] = (float4v){-INFINITY, -INFINITY, -INFINITY, -INFINITY};
    }
  }
  mx = fmaxf(mx, __shfl_xor(mx, 16));
  mx = fmaxf(mx, __shfl_xor(mx, 32));
  float sum = 0.f;
#pragma unroll
  for (int w = 0; w < 17; ++w)
#pragma unroll
    for (int r = 0; r < 4; ++r) {
      float e = exp2v(s[w][r] - mx); // logits pre-scaled by log2(e)
      s[w][r] = e; sum += e;
    }
  sum += __shfl_xor(sum, 16);
  sum += __shfl_xor(sum, 32);
  float inv = 1.f / sum;
#pragma unroll
  for (int w = 0; w < 17; ++w) {
    unsigned int u0 = cvtpk(s[w][0], s[w][1]);
    unsigned int u1 = cvtpk(s[w][2], s[w][3]);
    *(unsigned int*)(P + lrow * 576 + (((w * 16 + g * 4 + 0) * 2) ^ swz)) = u0;
    *(unsigned int*)(P + lrow * 576 + (((w * 16 + g * 4 + 2) * 2) ^ swz)) = u1;
  }
  // zero tail keys 272..287 (covers PV read-set exactly)
  *(unsigned int*)(P + lrow * 576 + (((272 + g * 4 + 0) * 2) ^ swz)) = 0u;
  *(unsigned int*)(P + lrow * 576 + (((272 + g * 4 + 2) * 2) ^ swz)) = 0u;

  // residual preload (issue-early: completes during PV)
  size_t rowbase = (size_t)(b * 256 + t) * 16 * 256;
  int col = wave * 32 + lrow;
  float xv0[4], xv1[4];
#pragma unroll
  for (int r = 0; r < 4; ++r) {
    xv0[r] = bf2f(xb[rowbase + (g * 4 + r) * 256 + col]);
    xv1[r] = bf2f(xb[rowbase + (g * 4 + r) * 256 + col + 16]);
  }

  asm volatile("s_waitcnt lgkmcnt(0)" ::: "memory");
  __builtin_amdgcn_sched_barrier(0);
  float4v o0 = z4, o1 = z4;
  int tn0 = (t - 8) * 16;
  const unsigned short* vbase = vT + (base * 32 / 4096 + lrow) * 4096; // (b*8+h)*32 + lrow rows
  __builtin_amdgcn_s_setprio(1);
#pragma unroll
  for (int c = 0; c < 9; ++c) {
    short8 pf = *(const short8*)(P + lrow * 576 + ((c * 64 + g * 16) ^ swz));
    short8 v0 = *(const short8*)(vbase + tn0 + c * 32 + g * 8);
    short8 v1 = *(const short8*)(vbase + (size_t)16 * 4096 + tn0 + c * 32 + g * 8);
    o0 = __builtin_amdgcn_mfma_f32_16x16x32_bf16(pf, v0, o0, 0, 0, 0);
    o1 = __builtin_amdgcn_mfma_f32_16x16x32_bf16(pf, v1, o1, 0, 0, 0);
  }
  __builtin_amdgcn_s_setprio(0);

  // val = ctx + x ; cross-wave LN over 256 cols
  float va0[4], va1[4];
#pragma unroll
  for (int r = 0; r < 4; ++r) {
    float invn = __shfl(inv, g * 4 + r);
    va0[r] = o0[r] * invn + xv0[r];
    va1[r] = o1[r] * invn + xv1[r];
  }
#pragma unroll
  for (int r = 0; r < 4; ++r) {
    float sm = va0[r] + va1[r];
    float sq = va0[r] * va0[r] + va1[r] * va1[r];
#pragma unroll
    for (int off = 1; off < 16; off <<= 1) {
      sm += __shfl_xor(sm, off);
      sq += __shfl_xor(sq, off);
    }
    if (lrow == 0) {
      stats[wave][g * 4 + r][0] = sm;
      stats[wave][g * 4 + r][1] = sq;
    }
  }
  __syncthreads();
  if (tid < 16) {
    float S = 0.f, Q = 0.f;
#pragma unroll
    for (int w2 = 0; w2 < 8; ++w2) { S += stats[w2][tid][0]; Q += stats[w2][tid][1]; }
    float mean = S * (1.f / 256.f);
    float var = Q * (1.f / 256.f) - mean * mean;
    mst[tid] = mean;
    rst[tid] = rsqrtf(var + EPS);
  }
  __syncthreads();
  float gv0 = gw[col], gv1 = gw[col + 16];
  float bv0 = bw[col], bv1 = bw[col + 16];
#pragma unroll
  for (int r = 0; r < 4; ++r) {
    int row = g * 4 + r;
    float mean = mst[row], rs = rst[row];
    yb[rowbase + row * 256 + col]      = f2bf((va0[r] - mean) * rs * gv0 + bv0);
    yb[rowbase + row * 256 + col + 16] = f2bf((va1[r] - mean) * rs * gv1 + bv1);
  }
}

// ---------------- FFN2 + residual + LN2, 512 thr, register-LN stats ----------------
__launch_bounds__(512, 2)
__global__ void ffn2_kernel(const unsigned short* __restrict__ hid,
                            const unsigned short* __restrict__ W2T,
                            const float* __restrict__ b2,
                            const unsigned short* __restrict__ yb,
                            const float* __restrict__ gw, const float* __restrict__ bw,
                            float* __restrict__ out) {
  constexpr int BM = 64, BN = 256, K = 1024, KP = K / 64;
  __shared__ char smem[(BM + BN) * 128]; // 40KB
  __shared__ float stats[8][32][2];
  __shared__ float mst[64], rst[64];
  const int tid = threadIdx.x;
  const int wave = tid >> 6, lane = tid & 63;
  const int lrow = lane & 15, g = lane >> 4;
  const int m0 = blockIdx.x * BM;
  const int wr = wave >> 2, wc = wave & 3; // 2M x 4N waves, wave tile 32x64
  char* As = smem;
  char* Bs = smem + BM * 128;
  float4v acc[2][4];
#pragma unroll
  for (int i = 0; i < 2; ++i)
#pragma unroll
    for (int j = 0; j < 4; ++j) acc[i][j] = (float4v){0.f, 0.f, 0.f, 0.f};

  const unsigned short* Abase = hid + (size_t)m0 * K;
  for (int ph = 0; ph < KP; ++ph) {
    if (ph) __syncthreads();
    stage_rows<BM, K, 512>(Abase, ph * 64, As, tid);
    stage_rows<BN, K, 512>(W2T, ph * 64, Bs, tid);
    __syncthreads();
#pragma unroll
    for (int ks = 0; ks < 2; ++ks) {
      short8 af[2], bf[4];
#pragma unroll
      for (int i = 0; i < 2; ++i) {
        int ar = wr * 32 + i * 16 + lrow;
        af[i] = *(const short8*)(As + ar * 128 + ((ks * 64 + g * 16) ^ ((ar & 7) << 4)));
      }
#pragma unroll
      for (int j = 0; j < 4; ++j) {
        int br = wc * 64 + j * 16 + lrow;
        bf[j] = *(const short8*)(Bs + br * 128 + ((ks * 64 + g * 16) ^ ((br & 7) << 4)));
      }
#pragma unroll
      for (int i = 0; i < 2; ++i)
#pragma unroll
        for (int j = 0; j < 4; ++j)
          acc[i][j] = __builtin_amdgcn_mfma_f32_16x16x32_bf16(af[i], bf[j], acc[i][j], 0, 0, 0);
    }
  }
  __syncthreads(); // staging LDS dead; safe to use stats

#pragma unroll
  for (int i = 0; i < 2; ++i)
#pragma unroll
    for (int j = 0; j < 4; ++j) {
      int col = wc * 64 + j * 16 + lrow;
      float bv = b2[col];
#pragma unroll
      for (int r = 0; r < 4; ++r) {
        int row = wr * 32 + i * 16 + g * 4 + r;
        acc[i][j][r] += bv + bf2f(yb[(size_t)(m0 + row) * 256 + col]);
      }
    }
#pragma unroll
  for (int i = 0; i < 2; ++i)
#pragma unroll
    for (int r = 0; r < 4; ++r) {
      float sm = acc[i][0][r] + acc[i][1][r] + acc[i][2][r] + acc[i][3][r];
      float sq = acc[i][0][r] * acc[i][0][r] + acc[i][1][r] * acc[i][1][r]
               + acc[i][2][r] * acc[i][2][r] + acc[i][3][r] * acc[i][3][r];
#pragma unroll
      for (int off = 1; off < 16; off <<= 1) {
        sm += __shfl_xor(sm, off);
        sq += __shfl_xor(sq, off);
      }
      if (lrow == 0) {
        stats[wave][i * 16 + g * 4 + r][0] = sm;
        stats[wave][i * 16 + g * 4 + r][1] = sq;
      }
    }
  __syncthreads();
  if (tid < 64) {
    int wrr = tid >> 5, rl = tid & 31;
    float S = 0.f, Q = 0.f;
#pragma unroll
    for (int w2 = 0; w2 < 4; ++w2) {
      S += stats[wrr * 4 + w2][rl][0];
      Q += stats[wrr * 4 + w2][rl][1];
    }
    float mean = S * (1.f / 256.f);
    float var = Q * (1.f / 256.f) - mean * mean;
    mst[tid] = mean;
    rst[tid] = rsqrtf(var + EPS);
  }
  __syncthreads();
  float gv[4], bev[4];
#pragma unroll
  for (int j = 0; j < 4; ++j) {
    int col = wc * 64 + j * 16 + lrow;
    gv[j] = gw[col]; bev[j] = bw[col];
  }
#pragma unroll
  for (int i = 0; i < 2; ++i)
#pragma unroll
    for (int r = 0; r < 4; ++r) {
      int rl = wr * 32 + i * 16 + g * 4 + r;
      float mean = mst[rl], rs = rst[rl];
#pragma unroll
      for (int j = 0; j < 4; ++j) {
        int col = wc * 64 + j * 16 + lrow;
        out[(size_t)(m0 + rl) * 256 + col] = (acc[i][j][r] - mean) * rs * gv[j] + bev[j];
      }
    }
}

extern "C" void kernel_launch(void* const* d_in, const int* in_sizes, int n_in,
                              void* d_out, int out_size, void* d_ws, size_t ws_size,
                              hipStream_t stream) {
  const float* x  = (const float*)d_in[0];
  const unsigned char* kpm = (const unsigned char*)d_in[1];
  const float* Wq = (const float*)d_in[2];
  const float* bq = (const float*)d_in[3];
  const float* Wk = (const float*)d_in[4];
  const float* bk = (const float*)d_in[5];
  const float* Wv = (const float*)d_in[6];
  const float* bv = (const float*)d_in[7];
  const float* W1 = (const float*)d_in[8];
  const float* b1 = (const float*)d_in[9];
  const float* W2 = (const float*)d_in[10];
  const float* b2 = (const float*)d_in[11];
  const float* g1 = (const float*)d_in[12];
  const float* be1= (const float*)d_in[13];
  const float* g2 = (const float*)d_in[14];
  const float* be2= (const float*)d_in[15];
  float* out = (float*)d_out;

  char* w = (char*)d_ws;
  const size_t MB = 1u << 20;
  unsigned short* xb   = (unsigned short*)(w);            // 8MB
  unsigned short* qhm  = (unsigned short*)(w + 8 * MB);   // 8MB
  unsigned short* khm  = (unsigned short*)(w + 16 * MB);  // 8MB
  unsigned short* vTb  = (unsigned short*)(w + 24 * MB);  // 8MB
  unsigned short* yb   = (unsigned short*)(w + 48 * MB);  // 8MB
  unsigned short* WqkvT = (unsigned short*)(w + 72 * MB); // 384KB [768][256]
  unsigned short* W1T = WqkvT + 196608;                   // 512KB [1024][256]
  unsigned short* W2T = W1T + 262144;                     // 512KB [256][1024]
  unsigned short* kpm16 = W2T + 262144;                   // 2KB
  float* bqkv = (float*)(kpm16 + 1024);                   // 3KB
  unsigned short* hid = qhm;                              // 32MB overlay 8..40MB (q/k/vT dead after attn)

  prep_kernel<<<4805, 256, 0, stream>>>(x, kpm, Wq, Wk, Wv, W1, W2, bq, bk, bv,
                                        xb, WqkvT, W1T, W2T, kpm16, bqkv);
  gemm_kernel<0><<<dim3(128, 6), 256, 0, stream>>>(xb, WqkvT, bqkv, qhm, khm, vTb, nullptr);
  attn_ln_kernel<<<1024, 512, 0, stream>>>(qhm, khm, vTb, kpm16, xb, g1, be1, yb);
  gemm_kernel<1><<<dim3(128, 8), 256, 0, stream>>>(yb, W1T, b1, nullptr, nullptr, nullptr, hid);
  ffn2_kernel<<<256, 512, 0, stream>>>(hid, W2T, b2, yb, g2, be2, out);
}

// Round 12
// 100.847 us; speedup vs baseline: 1.2017x; 1.0136x over previous
//
#include <hip/hip_runtime.h>
#include <hip/hip_bf16.h>
#include <math.h>

typedef __attribute__((ext_vector_type(8))) short short8;
typedef __attribute__((ext_vector_type(4))) float float4v;

#define BB 4
#define TT 256
#define NDET 16
#define HH 256
#define NHEAD 8
#define DD 32
#define FFNDIM 1024
#define ROWS (BB*TT*NDET) /* 16384 */
#define EPS 1e-5f

// f32 -> bf16 round-to-nearest-even
__device__ __forceinline__ unsigned short f2bf(float f) {
  unsigned int u = __float_as_uint(f);
  u += 0x7fffu + ((u >> 16) & 1u);
  return (unsigned short)(u >> 16);
}
__device__ __forceinline__ float bf2f(unsigned short u) {
  return __uint_as_float((unsigned int)u << 16);
}
// v_exp_f32 computes 2^x natively
__device__ __forceinline__ float exp2v(float x) {
  float r; asm("v_exp_f32 %0, %1" : "=v"(r) : "v"(x)); return r;
}
// pack two f32 -> two bf16 in one reg (lo in low half)
__device__ __forceinline__ unsigned int cvtpk(float lo, float hi) {
  unsigned int r; asm("v_cvt_pk_bf16_f32 %0, %1, %2" : "=v"(r) : "v"(lo), "v"(hi)); return r;
}

// ---------------- prep: weight transposes + x cvt + kpm pack + bias concat ----------------
__device__ __forceinline__ void wt_tile(const float* __restrict__ W, unsigned short* __restrict__ WT,
                                        int K, int N, int k0, int n0,
                                        float (*tile)[33], int tid) {
  {
    int r = tid >> 3, c4 = (tid & 7) * 4;
    float4 in = *(const float4*)(W + (size_t)(k0 + r) * N + n0 + c4);
    tile[r][c4 + 0] = in.x; tile[r][c4 + 1] = in.y;
    tile[r][c4 + 2] = in.z; tile[r][c4 + 3] = in.w;
  }
  __syncthreads();
  {
    int n = tid >> 3, k4 = (tid & 7) * 4;
    ushort4 o;
    o.x = f2bf(tile[k4 + 0][n]); o.y = f2bf(tile[k4 + 1][n]);
    o.z = f2bf(tile[k4 + 2][n]); o.w = f2bf(tile[k4 + 3][n]);
    *(ushort4*)(WT + (size_t)(n0 + n) * K + k0 + k4) = o;
  }
}

__global__ void prep_kernel(const float* __restrict__ x, const unsigned char* __restrict__ kpm,
                            const float* __restrict__ Wq, const float* __restrict__ Wk,
                            const float* __restrict__ Wv, const float* __restrict__ W1,
                            const float* __restrict__ W2,
                            const float* __restrict__ bq, const float* __restrict__ bk,
                            const float* __restrict__ bv,
                            unsigned short* __restrict__ xb, unsigned short* __restrict__ WqkvT,
                            unsigned short* __restrict__ W1T, unsigned short* __restrict__ W2T,
                            unsigned short* __restrict__ kpm16, float* __restrict__ bqkv) {
  __shared__ float tile[32][33];
  int bid = blockIdx.x, tid = threadIdx.x;
  if (bid < 4096) {
    size_t i = (size_t)(bid * 256 + tid) * 4;
    float4 v = *(const float4*)(x + i);
    ushort4 o = { f2bf(v.x), f2bf(v.y), f2bf(v.z), f2bf(v.w) };
    *(ushort4*)(xb + i) = o;
  } else if (bid < 4288) {
    int t = bid - 4096;
    int wsel = t >> 6, tt = t & 63;
    const float* W = (wsel == 0) ? Wq : (wsel == 1) ? Wk : Wv;
    wt_tile(W, WqkvT + wsel * 65536, 256, 256, (tt >> 3) * 32, (tt & 7) * 32, tile, tid);
  } else if (bid < 4544) {
    int tt = bid - 4288; // W1 [256][1024]
    wt_tile(W1, W1T, 256, 1024, (tt >> 5) * 32, (tt & 31) * 32, tile, tid);
  } else if (bid < 4800) {
    int tt = bid - 4544; // W2 [1024][256]
    wt_tile(W2, W2T, 1024, 256, (tt >> 3) * 32, (tt & 7) * 32, tile, tid);
  } else if (bid < 4804) {
    int w = (bid - 4800) * 256 + tid;
    uint4 u = *(const uint4*)(kpm + (size_t)w * 16);
    unsigned int a[4] = {u.x, u.y, u.z, u.w};
    unsigned int bits = 0;
#pragma unroll
    for (int m = 0; m < 16; ++m)
      if ((a[m >> 2] >> ((m & 3) * 8)) & 0xffu) bits |= (1u << m);
    kpm16[w] = (unsigned short)bits;
  } else {
    bqkv[tid] = bq[tid];
    bqkv[256 + tid] = bk[tid];
    bqkv[512 + tid] = bv[tid];
  }
}

// -------- stage NROWS x 64 bf16 cols from row-major src (stride K) into LDS --------
// LDS linear [r][128B]; source pre-swizzled so swizzled ds_read works (rule #21).
template<int NROWS, int K, int NT>
__device__ __forceinline__ void stage_rows(const unsigned short* __restrict__ src, int kcol0,
                                           char* ldsbase, int tid) {
  constexpr int ISS = NROWS * 8 / NT;
  int wave = tid >> 6;
#pragma unroll
  for (int i = 0; i < ISS; ++i) {
    int flat = i * (NT * 16) + tid * 16;
    int r = flat >> 7;
    int cb = flat & 127;
    int scb = cb ^ ((r & 7) << 4);
    const unsigned short* g = src + (size_t)r * K + kcol0 + (scb >> 1);
    char* l = ldsbase + i * (NT * 16) + wave * 1024; // wave-uniform; HW adds lane*16
    __builtin_amdgcn_global_load_lds((const __attribute__((address_space(1))) void*)g,
                                     (__attribute__((address_space(3))) void*)l, 16, 0, 0);
  }
}

// ---------------- MFMA GEMM (m97 structure), 256 thr, tile 128x128, 4 blocks/CU ----------------
// EPI 0: QKV fused (N=768): (acc+bias)*scale -> q/k head-major bf16, V written pre-transposed vT
// EPI 1: relu(acc+bias) -> bf16 hid [M][1024]
template<int EPI>
__launch_bounds__(256, 4)
__global__ void gemm_kernel(const unsigned short* __restrict__ A,
                            const unsigned short* __restrict__ Bt,
                            const float* __restrict__ bias,
                            unsigned short* __restrict__ q_o, unsigned short* __restrict__ k_o,
                            unsigned short* __restrict__ vT_o,
                            unsigned short* __restrict__ outb) {
  constexpr int BM = 128, BN = 128, K = 256, KP = K / 64;
  __shared__ char smem[(BM + BN) * 128];
  const int tid = threadIdx.x;
  const int wave = tid >> 6, lane = tid & 63;
  const int lrow = lane & 15, g = lane >> 4;
  const int m0 = blockIdx.x * BM;
  const int n0 = blockIdx.y * BN;
  const int wr = wave >> 1, wc = wave & 1;
  char* As = smem;
  char* Bs = smem + BM * 128;
  float4v acc[4][4];
#pragma unroll
  for (int i = 0; i < 4; ++i)
#pragma unroll
    for (int j = 0; j < 4; ++j) acc[i][j] = (float4v){0.f, 0.f, 0.f, 0.f};

  const unsigned short* Abase = A + (size_t)m0 * K;
  const unsigned short* Bbase = Bt + (size_t)n0 * K;
  for (int ph = 0; ph < KP; ++ph) {
    if (ph) __syncthreads();
    stage_rows<BM, K, 256>(Abase, ph * 64, As, tid);
    stage_rows<BN, K, 256>(Bbase, ph * 64, Bs, tid);
    __syncthreads();
#pragma unroll
    for (int ks = 0; ks < 2; ++ks) {
      short8 af[4], bf[4];
#pragma unroll
      for (int i = 0; i < 4; ++i) {
        int ar = wr * 64 + i * 16 + lrow;
        af[i] = *(const short8*)(As + ar * 128 + ((ks * 64 + g * 16) ^ ((ar & 7) << 4)));
      }
#pragma unroll
      for (int j = 0; j < 4; ++j) {
        int br = wc * 64 + j * 16 + lrow;
        bf[j] = *(const short8*)(Bs + br * 128 + ((ks * 64 + g * 16) ^ ((br & 7) << 4)));
      }
#pragma unroll
      for (int i = 0; i < 4; ++i)
#pragma unroll
        for (int j = 0; j < 4; ++j)
          acc[i][j] = __builtin_amdgcn_mfma_f32_16x16x32_bf16(af[i], bf[j], acc[i][j], 0, 0, 0);
    }
  }

  if (EPI == 0) {
    const float QS = 0.17677669529663687f * 1.4426950408889634f; // (1/sqrt(32))*log2(e)
#pragma unroll
    for (int i = 0; i < 4; ++i)
#pragma unroll
      for (int j = 0; j < 4; ++j) {
        int C = n0 + wc * 64 + j * 16 + lrow;
        float bv = bias[C];
        int proj = C >> 8, cc = C & 255;  // wave-uniform proj
        int h = cc >> 5, d = cc & 31;
        if (proj == 2) { // V: write pre-transposed vT[bh][d][tn], 4 consecutive tn packed
          int grow0 = m0 + wr * 64 + i * 16 + g * 4;
          int b = grow0 >> 12, tn0 = grow0 & 4095;
          ushort4 o;
          o.x = f2bf(acc[i][j][0] + bv);
          o.y = f2bf(acc[i][j][1] + bv);
          o.z = f2bf(acc[i][j][2] + bv);
          o.w = f2bf(acc[i][j][3] + bv);
          *(ushort4*)(vT_o + ((size_t)(b * 8 + h) * 32 + d) * 4096 + tn0) = o;
        } else {
          unsigned short* om = (proj == 0) ? q_o : k_o;
          float sc = (proj == 0) ? QS : 1.f;
#pragma unroll
          for (int r = 0; r < 4; ++r) {
            int grow = m0 + wr * 64 + i * 16 + g * 4 + r;
            int b = grow >> 12, tn = grow & 4095;
            om[(size_t)((b * 8 + h) * 4096 + tn) * 32 + d] = f2bf((acc[i][j][r] + bv) * sc);
          }
        }
      }
  } else {
#pragma unroll
    for (int i = 0; i < 4; ++i)
#pragma unroll
      for (int j = 0; j < 4; ++j) {
        int C = n0 + wc * 64 + j * 16 + lrow;
        float bv = bias[C];
#pragma unroll
        for (int r = 0; r < 4; ++r) {
          int grow = m0 + wr * 64 + i * 16 + g * 4 + r;
          outb[(size_t)grow * FFNDIM + C] = f2bf(fmaxf(acc[i][j][r] + bv, 0.f));
        }
      }
  }
}

// ---------------- windowed attention + residual + LN1 fused (R11, unchanged) ----------------
__launch_bounds__(512, 4)
__global__ void attn_ln_kernel(const unsigned short* __restrict__ qb,
                               const unsigned short* __restrict__ kb,
                               const unsigned short* __restrict__ vT,
                               const unsigned short* __restrict__ kpm16,
                               const unsigned short* __restrict__ xb,
                               const float* __restrict__ gw, const float* __restrict__ bw,
                               unsigned short* __restrict__ yb) {
  __shared__ char Pall[8][9216]; // per-wave [16 n][288 key] bf16, 576B rows, 64B-closed swizzle
  __shared__ float stats[8][16][2];
  __shared__ float mst[16], rst[16];
  int tid = threadIdx.x;
  int wave = tid >> 6, l = tid & 63;
  // XCD-bijective swizzle (proven R6: FETCH 78->17MB)
  int lid = (blockIdx.x & 7) * 128 + (blockIdx.x >> 3);
  int t = lid & 255, b = lid >> 8;
  char* P = Pall[wave];
  int lrow = l & 15, g = l >> 4;
  int swz = (lrow & 3) << 4; // closed within 64B blocks (~4-way conflicts, buys occupancy)
  size_t base = (size_t)(b * 8 + wave) * 4096;
  short8 qf = *(const short8*)(qb + (base + t * 16 + lrow) * 32 + g * 8);
  const float4v z4 = {0.f, 0.f, 0.f, 0.f};
  float4v s[17];
  float mx = -INFINITY;
#pragma unroll
  for (int w = 0; w < 17; ++w) {
    int j = t + w - 8;
    if (j >= 0 && j < 256) {
      short8 kf = *(const short8*)(kb + (base + j * 16 + lrow) * 32 + g * 8);
      float4v sv = __builtin_amdgcn_mfma_f32_16x16x32_bf16(kf, qf, z4, 0, 0, 0);
      unsigned int mw = kpm16[b * 256 + j];
#pragma unroll
      for (int r = 0; r < 4; ++r)
        if ((mw >> (g * 4 + r)) & 1u) sv[r] = -INFINITY;
      s[w] = sv;
#pragma unroll
      for (int r = 0; r < 4; ++r) mx = fmaxf(mx, sv[r]);
    } else {
      s[w] = (float4v){-INFINITY, -INFINITY, -INFINITY, -INFINITY};
    }
  }
  mx = fmaxf(mx, __shfl_xor(mx, 16));
  mx = fmaxf(mx, __shfl_xor(mx, 32));
  float sum = 0.f;
#pragma unroll
  for (int w = 0; w < 17; ++w)
#pragma unroll
    for (int r = 0; r < 4; ++r) {
      float e = exp2v(s[w][r] - mx); // logits pre-scaled by log2(e)
      s[w][r] = e; sum += e;
    }
  sum += __shfl_xor(sum, 16);
  sum += __shfl_xor(sum, 32);
  float inv = 1.f / sum;
#pragma unroll
  for (int w = 0; w < 17; ++w) {
    unsigned int u0 = cvtpk(s[w][0], s[w][1]);
    unsigned int u1 = cvtpk(s[w][2], s[w][3]);
    *(unsigned int*)(P + lrow * 576 + (((w * 16 + g * 4 + 0) * 2) ^ swz)) = u0;
    *(unsigned int*)(P + lrow * 576 + (((w * 16 + g * 4 + 2) * 2) ^ swz)) = u1;
  }
  // zero tail keys 272..287 (covers PV read-set exactly)
  *(unsigned int*)(P + lrow * 576 + (((272 + g * 4 + 0) * 2) ^ swz)) = 0u;
  *(unsigned int*)(P + lrow * 576 + (((272 + g * 4 + 2) * 2) ^ swz)) = 0u;

  // residual preload (issue-early: completes during PV)
  size_t rowbase = (size_t)(b * 256 + t) * 16 * 256;
  int col = wave * 32 + lrow;
  float xv0[4], xv1[4];
#pragma unroll
  for (int r = 0; r < 4; ++r) {
    xv0[r] = bf2f(xb[rowbase + (g * 4 + r) * 256 + col]);
    xv1[r] = bf2f(xb[rowbase + (g * 4 + r) * 256 + col + 16]);
  }

  asm volatile("s_waitcnt lgkmcnt(0)" ::: "memory");
  __builtin_amdgcn_sched_barrier(0);
  float4v o0 = z4, o1 = z4;
  int tn0 = (t - 8) * 16;
  const unsigned short* vbase = vT + (base * 32 / 4096 + lrow) * 4096; // (b*8+h)*32 + lrow rows
  __builtin_amdgcn_s_setprio(1);
#pragma unroll
  for (int c = 0; c < 9; ++c) {
    short8 pf = *(const short8*)(P + lrow * 576 + ((c * 64 + g * 16) ^ swz));
    short8 v0 = *(const short8*)(vbase + tn0 + c * 32 + g * 8);
    short8 v1 = *(const short8*)(vbase + (size_t)16 * 4096 + tn0 + c * 32 + g * 8);
    o0 = __builtin_amdgcn_mfma_f32_16x16x32_bf16(pf, v0, o0, 0, 0, 0);
    o1 = __builtin_amdgcn_mfma_f32_16x16x32_bf16(pf, v1, o1, 0, 0, 0);
  }
  __builtin_amdgcn_s_setprio(0);

  // val = ctx + x ; cross-wave LN over 256 cols
  float va0[4], va1[4];
#pragma unroll
  for (int r = 0; r < 4; ++r) {
    float invn = __shfl(inv, g * 4 + r);
    va0[r] = o0[r] * invn + xv0[r];
    va1[r] = o1[r] * invn + xv1[r];
  }
#pragma unroll
  for (int r = 0; r < 4; ++r) {
    float sm = va0[r] + va1[r];
    float sq = va0[r] * va0[r] + va1[r] * va1[r];
#pragma unroll
    for (int off = 1; off < 16; off <<= 1) {
      sm += __shfl_xor(sm, off);
      sq += __shfl_xor(sq, off);
    }
    if (lrow == 0) {
      stats[wave][g * 4 + r][0] = sm;
      stats[wave][g * 4 + r][1] = sq;
    }
  }
  __syncthreads();
  if (tid < 16) {
    float S = 0.f, Q = 0.f;
#pragma unroll
    for (int w2 = 0; w2 < 8; ++w2) { S += stats[w2][tid][0]; Q += stats[w2][tid][1]; }
    float mean = S * (1.f / 256.f);
    float var = Q * (1.f / 256.f) - mean * mean;
    mst[tid] = mean;
    rst[tid] = rsqrtf(var + EPS);
  }
  __syncthreads();
  float gv0 = gw[col], gv1 = gw[col + 16];
  float bv0 = bw[col], bv1 = bw[col + 16];
#pragma unroll
  for (int r = 0; r < 4; ++r) {
    int row = g * 4 + r;
    float mean = mst[row], rs = rst[row];
    yb[rowbase + row * 256 + col]      = f2bf((va0[r] - mean) * rs * gv0 + bv0);
    yb[rowbase + row * 256 + col + 16] = f2bf((va1[r] - mean) * rs * gv1 + bv1);
  }
}

// ---------------- FFN2 + residual + LN2: BM=32 -> 512 blocks (2/CU), 512 thr ----------------
__launch_bounds__(512, 4)
__global__ void ffn2_kernel(const unsigned short* __restrict__ hid,
                            const unsigned short* __restrict__ W2T,
                            const float* __restrict__ b2,
                            const unsigned short* __restrict__ yb,
                            const float* __restrict__ gw, const float* __restrict__ bw,
                            float* __restrict__ out) {
  constexpr int BM = 32, BN = 256, K = 1024, KP = K / 64;
  __shared__ char smem[(BM + BN) * 128]; // 36KB
  __shared__ float stats[8][16][2];
  __shared__ float mst[32], rst[32];
  const int tid = threadIdx.x;
  const int wave = tid >> 6, lane = tid & 63;
  const int lrow = lane & 15, g = lane >> 4;
  const int m0 = blockIdx.x * BM;
  const int wr = wave >> 2, wc = wave & 3; // 2M x 4N waves, wave tile 16x64
  char* As = smem;
  char* Bs = smem + BM * 128;
  float4v acc[4];
#pragma unroll
  for (int j = 0; j < 4; ++j) acc[j] = (float4v){0.f, 0.f, 0.f, 0.f};

  const unsigned short* Abase = hid + (size_t)m0 * K;
  for (int ph = 0; ph < KP; ++ph) {
    if (ph) __syncthreads();
    // A: 32 rows x 128B = 4KB staged by threads 0..255 (wave-uniform branch)
    if (tid < 256) {
      int flat = tid * 16;
      int r = flat >> 7;
      int cb = flat & 127;
      int scb = cb ^ ((r & 7) << 4);
      const unsigned short* gp = Abase + (size_t)r * K + ph * 64 + (scb >> 1);
      char* lp = As + wave * 1024; // waves 0..3; HW adds lane*16
      __builtin_amdgcn_global_load_lds((const __attribute__((address_space(1))) void*)gp,
                                       (__attribute__((address_space(3))) void*)lp, 16, 0, 0);
    }
    stage_rows<BN, K, 512>(W2T, ph * 64, Bs, tid);
    __syncthreads();
#pragma unroll
    for (int ks = 0; ks < 2; ++ks) {
      short8 af, bf[4];
      {
        int ar = wr * 16 + lrow;
        af = *(const short8*)(As + ar * 128 + ((ks * 64 + g * 16) ^ ((ar & 7) << 4)));
      }
#pragma unroll
      for (int j = 0; j < 4; ++j) {
        int br = wc * 64 + j * 16 + lrow;
        bf[j] = *(const short8*)(Bs + br * 128 + ((ks * 64 + g * 16) ^ ((br & 7) << 4)));
      }
#pragma unroll
      for (int j = 0; j < 4; ++j)
        acc[j] = __builtin_amdgcn_mfma_f32_16x16x32_bf16(af, bf[j], acc[j], 0, 0, 0);
    }
  }
  __syncthreads(); // staging LDS dead; safe to use stats

#pragma unroll
  for (int j = 0; j < 4; ++j) {
    int col = wc * 64 + j * 16 + lrow;
    float bv = b2[col];
#pragma unroll
    for (int r = 0; r < 4; ++r) {
      int row = wr * 16 + g * 4 + r;
      acc[j][r] += bv + bf2f(yb[(size_t)(m0 + row) * 256 + col]);
    }
  }
#pragma unroll
  for (int r = 0; r < 4; ++r) {
    float sm = acc[0][r] + acc[1][r] + acc[2][r] + acc[3][r];
    float sq = acc[0][r] * acc[0][r] + acc[1][r] * acc[1][r]
             + acc[2][r] * acc[2][r] + acc[3][r] * acc[3][r];
#pragma unroll
    for (int off = 1; off < 16; off <<= 1) {
      sm += __shfl_xor(sm, off);
      sq += __shfl_xor(sq, off);
    }
    if (lrow == 0) {
      stats[wave][g * 4 + r][0] = sm;
      stats[wave][g * 4 + r][1] = sq;
    }
  }
  __syncthreads();
  if (tid < 32) {
    int wrr = tid >> 4;
    float S = 0.f, Q = 0.f;
#pragma unroll
    for (int w2 = 0; w2 < 4; ++w2) {
      S += stats[wrr * 4 + w2][tid & 15][0];
      Q += stats[wrr * 4 + w2][tid & 15][1];
    }
    float mean = S * (1.f / 256.f);
    float var = Q * (1.f / 256.f) - mean * mean;
    mst[tid] = mean;
    rst[tid] = rsqrtf(var + EPS);
  }
  __syncthreads();
#pragma unroll
  for (int r = 0; r < 4; ++r) {
    int rl = wr * 16 + g * 4 + r;
    float mean = mst[rl], rs = rst[rl];
#pragma unroll
    for (int j = 0; j < 4; ++j) {
      int col = wc * 64 + j * 16 + lrow;
      out[(size_t)(m0 + rl) * 256 + col] = (acc[j][r] - mean) * rs * gw[col] + bw[col];
    }
  }
}

extern "C" void kernel_launch(void* const* d_in, const int* in_sizes, int n_in,
                              void* d_out, int out_size, void* d_ws, size_t ws_size,
                              hipStream_t stream) {
  const float* x  = (const float*)d_in[0];
  const unsigned char* kpm = (const unsigned char*)d_in[1];
  const float* Wq = (const float*)d_in[2];
  const float* bq = (const float*)d_in[3];
  const float* Wk = (const float*)d_in[4];
  const float* bk = (const float*)d_in[5];
  const float* Wv = (const float*)d_in[6];
  const float* bv = (const float*)d_in[7];
  const float* W1 = (const float*)d_in[8];
  const float* b1 = (const float*)d_in[9];
  const float* W2 = (const float*)d_in[10];
  const float* b2 = (const float*)d_in[11];
  const float* g1 = (const float*)d_in[12];
  const float* be1= (const float*)d_in[13];
  const float* g2 = (const float*)d_in[14];
  const float* be2= (const float*)d_in[15];
  float* out = (float*)d_out;

  char* w = (char*)d_ws;
  const size_t MB = 1u << 20;
  unsigned short* xb   = (unsigned short*)(w);            // 8MB
  unsigned short* qhm  = (unsigned short*)(w + 8 * MB);   // 8MB
  unsigned short* khm  = (unsigned short*)(w + 16 * MB);  // 8MB
  unsigned short* vTb  = (unsigned short*)(w + 24 * MB);  // 8MB
  unsigned short* yb   = (unsigned short*)(w + 48 * MB);  // 8MB
  unsigned short* WqkvT = (unsigned short*)(w + 72 * MB); // 384KB [768][256]
  unsigned short* W1T = WqkvT + 196608;                   // 512KB [1024][256]
  unsigned short* W2T = W1T + 262144;                     // 512KB [256][1024]
  unsigned short* kpm16 = W2T + 262144;                   // 2KB
  float* bqkv = (float*)(kpm16 + 1024);                   // 3KB
  unsigned short* hid = qhm;                              // 32MB overlay 8..40MB (q/k/vT dead after attn)

  prep_kernel<<<4805, 256, 0, stream>>>(x, kpm, Wq, Wk, Wv, W1, W2, bq, bk, bv,
                                        xb, WqkvT, W1T, W2T, kpm16, bqkv);
  gemm_kernel<0><<<dim3(128, 6), 256, 0, stream>>>(xb, WqkvT, bqkv, qhm, khm, vTb, nullptr);
  attn_ln_kernel<<<1024, 512, 0, stream>>>(qhm, khm, vTb, kpm16, xb, g1, be1, yb);
  gemm_kernel<1><<<dim3(128, 8), 256, 0, stream>>>(yb, W1T, b1, nullptr, nullptr, nullptr, hid);
  ffn2_kernel<<<512, 512, 0, stream>>>(hid, W2T, b2, yb, g2, be2, out);
}